// Round 1
// baseline (107.078 us; speedup 1.0000x reference)
//
#include <hip/hip_runtime.h>
#include <math.h>

// x: [B=16, C=2048, H=64, W=64] fp32. H*W = 4096 contiguous per channel.
// Kernel 1: per-channel mean + max -> ws. 32768 blocks x 256 threads.
__global__ __launch_bounds__(256) void pool_kernel(const float* __restrict__ x,
                                                   float* __restrict__ mean_out,
                                                   float* __restrict__ max_out) {
    const int bc = blockIdx.x;                       // 0..32767  (b*2048 + c)
    const float4* base4 = (const float4*)(x + (size_t)bc * 4096);
    const int tid = threadIdx.x;                     // 0..255

    float s = 0.f;
    float m = -INFINITY;
#pragma unroll
    for (int i = 0; i < 4; ++i) {                    // 1024 float4s / 256 threads
        float4 v = base4[tid + i * 256];
        s += (v.x + v.y) + (v.z + v.w);
        m = fmaxf(m, fmaxf(fmaxf(v.x, v.y), fmaxf(v.z, v.w)));
    }
    // wave64 butterfly reduce
#pragma unroll
    for (int off = 32; off > 0; off >>= 1) {
        s += __shfl_down(s, off, 64);
        m = fmaxf(m, __shfl_down(m, off, 64));
    }
    __shared__ float ss[4];
    __shared__ float sm[4];
    const int wave = tid >> 6;
    if ((tid & 63) == 0) { ss[wave] = s; sm[wave] = m; }
    __syncthreads();
    if (tid == 0) {
        float ts = (ss[0] + ss[1]) + (ss[2] + ss[3]);
        float tm = fmaxf(fmaxf(sm[0], sm[1]), fmaxf(sm[2], sm[3]));
        mean_out[bc] = ts * (1.0f / 4096.0f);
        max_out[bc]  = tm;
    }
}

// Kernel 2: SE branch on [B, K=256] with Kr=128. One block per batch element.
// f[k]   = sum_o pooled[b][k*8+o] * w_ch[o]
// h[j]   = relu(sum_k f_avg[k]*w1[j][k]) + relu(sum_k f_max[k]*w1[j][k])
// y[k]   = sigmoid(sum_j h[j]*w2[k][j])
// out[b][k*8+o] = y[k]  for o in 0..7
__global__ __launch_bounds__(256) void se_kernel(const float* __restrict__ mean_in,
                                                 const float* __restrict__ max_in,
                                                 const float* __restrict__ w_ch,
                                                 const float* __restrict__ w1,
                                                 const float* __restrict__ w2,
                                                 float* __restrict__ out) {
    const int b = blockIdx.x;        // 0..15
    const int tid = threadIdx.x;     // 0..255

    __shared__ float fa[256];
    __shared__ float fm[256];
    __shared__ float hs[128];
    __shared__ float wc[8];
    if (tid < 8) wc[tid] = w_ch[tid];
    __syncthreads();

    {   // orientation contraction: each thread owns one k
        const float* pa = mean_in + b * 2048 + tid * 8;
        const float* pm = max_in  + b * 2048 + tid * 8;
        float sa = 0.f, sx = 0.f;
#pragma unroll
        for (int o = 0; o < 8; ++o) {
            sa += pa[o] * wc[o];
            sx += pm[o] * wc[o];
        }
        fa[tid] = sa;
        fm[tid] = sx;
    }
    __syncthreads();

    if (tid < 128) {                 // first matvec, both branches share w1 read
        const float* w1r = w1 + tid * 256;
        float sa = 0.f, sx = 0.f;
        for (int k = 0; k < 256; ++k) {
            float w = w1r[k];
            sa += fa[k] * w;
            sx += fm[k] * w;
        }
        hs[tid] = fmaxf(sa, 0.f) + fmaxf(sx, 0.f);   // relu then sum (w2 is linear)
    }
    __syncthreads();

    {   // second matvec + sigmoid + 8-way repeat
        const float* w2r = w2 + tid * 128;
        float s = 0.f;
        for (int j = 0; j < 128; ++j) s += hs[j] * w2r[j];
        float y = 1.0f / (1.0f + expf(-s));
        float4 v = make_float4(y, y, y, y);
        float4* o4 = (float4*)(out + b * 2048 + tid * 8);
        o4[0] = v;
        o4[1] = v;
    }
}

extern "C" void kernel_launch(void* const* d_in, const int* in_sizes, int n_in,
                              void* d_out, int out_size, void* d_ws, size_t ws_size,
                              hipStream_t stream) {
    const float* x    = (const float*)d_in[0];   // [16,2048,64,64]
    const float* w_ch = (const float*)d_in[1];   // [8]
    const float* w1   = (const float*)d_in[2];   // [128,256]
    const float* w2   = (const float*)d_in[3];   // [256,128]
    float* out = (float*)d_out;                  // [16,2048] (as [B,C,1,1])

    float* mean_ws = (float*)d_ws;               // 32768 floats
    float* max_ws  = mean_ws + 32768;            // 32768 floats

    pool_kernel<<<32768, 256, 0, stream>>>(x, mean_ws, max_ws);
    se_kernel<<<16, 256, 0, stream>>>(mean_ws, max_ws, w_ch, w1, w2, out);
}